// Round 1
// baseline (31.481 us; speedup 1.0000x reference)
//
#include <hip/hip_runtime.h>
#include <hip/hip_bf16.h>

// Problem constants (from reference): B=16, S=2048, D=512
// inputs: x [B,S,D] f32, input_ids [B,S] int, start_token_id int scalar,
//         control_emb [4, D] f32, sequence_emb [1003, D] f32
// output: [B,S,D] f32

#define S_LEN 2048
#define D_DIM 512
#define D4 (D_DIM / 4)          // 128 float4 per row
#define SEQ_START 4
#define NUM_SEQ 1003
#define SCAN_THREADS 256
#define CHUNK (S_LEN / SCAN_THREADS)   // 8 positions per thread

// Kernel 1: per-row inclusive max-scan of start markers -> code per (b,s).
// code >= 0  : use sequence_emb[code]
// code == -1 : zero embedding
// code <= -2 : use control_emb[-2 - code]
__global__ void __launch_bounds__(SCAN_THREADS)
alpe_scan_kernel(const int* __restrict__ ids,
                 const int* __restrict__ start_tok,
                 int* __restrict__ codes) {
    const int b = blockIdx.x;
    const int t = threadIdx.x;
    const int st = *start_tok;

    __shared__ int tmax[SCAN_THREADS];

    const int base = t * CHUNK;
    int local[CHUNK];
    int m = -1;
    #pragma unroll
    for (int k = 0; k < CHUNK; ++k) {
        const int j = base + k;
        const int id = ids[b * S_LEN + j];
        const int mk = (id == st && j >= SEQ_START) ? j : -1;
        local[k] = mk;
        m = max(m, mk);
    }
    tmax[t] = m;
    __syncthreads();

    // Hillis-Steele inclusive max-scan over the 256 per-thread maxima.
    for (int off = 1; off < SCAN_THREADS; off <<= 1) {
        const int other = (t >= off) ? tmax[t - off] : -1;
        __syncthreads();
        tmax[t] = max(tmax[t], other);
        __syncthreads();
    }
    int carry = (t == 0) ? -1 : tmax[t - 1];   // exclusive prefix for my chunk

    #pragma unroll
    for (int k = 0; k < CHUNK; ++k) {
        const int i = base + k;
        carry = max(carry, local[k]);
        int code;
        if (carry >= 0) {
            const int rel = i - carry;
            if (rel < NUM_SEQ) code = rel;
            else               code = (i < SEQ_START) ? (-2 - i) : -1;
        } else {
            code = (i < SEQ_START) ? (-2 - i) : -1;
        }
        codes[b * S_LEN + i] = code;
    }
}

// Kernel 2: out = x + emb[code], vectorized float4, grid-stride.
__global__ void __launch_bounds__(256)
alpe_add_kernel(const float4* __restrict__ x,
                const float4* __restrict__ ctrl,
                const float4* __restrict__ seq,
                const int* __restrict__ codes,
                float4* __restrict__ out,
                int total) {
    int idx = blockIdx.x * blockDim.x + threadIdx.x;
    const int stride = gridDim.x * blockDim.x;
    for (; idx < total; idx += stride) {
        const int d4 = idx & (D4 - 1);
        const int bs = idx >> 7;          // log2(D4) = 7
        const int code = codes[bs];
        const float4 xv = x[idx];
        float4 e = make_float4(0.f, 0.f, 0.f, 0.f);
        if (code >= 0) {
            e = seq[code * D4 + d4];
        } else if (code <= -2) {
            e = ctrl[(-2 - code) * D4 + d4];
        }
        out[idx] = make_float4(xv.x + e.x, xv.y + e.y, xv.z + e.z, xv.w + e.w);
    }
}

extern "C" void kernel_launch(void* const* d_in, const int* in_sizes, int n_in,
                              void* d_out, int out_size, void* d_ws, size_t ws_size,
                              hipStream_t stream) {
    const float* x          = (const float*)d_in[0];
    const int*   input_ids  = (const int*)d_in[1];
    const int*   start_tok  = (const int*)d_in[2];
    const float* ctrl       = (const float*)d_in[3];
    const float* seq        = (const float*)d_in[4];
    float*       out        = (float*)d_out;

    const int B = in_sizes[1] / S_LEN;      // 16
    int* codes = (int*)d_ws;                // B*S ints = 128 KB

    alpe_scan_kernel<<<B, SCAN_THREADS, 0, stream>>>(input_ids, start_tok, codes);

    const int total = B * S_LEN * D4;       // float4 count = 4,194,304
    const int blocks = 2048;
    alpe_add_kernel<<<blocks, 256, 0, stream>>>(
        (const float4*)x, (const float4*)ctrl, (const float4*)seq,
        codes, (float4*)out, total);
}